// Round 8
// baseline (340.072 us; speedup 1.0000x reference)
//
#include <hip/hip_runtime.h>
#include <math.h>

// Problem constants (fixed by the reference)
#define NBATCH 16
#define CCH    128     // channels C
#define HW     2304    // 48*48 tokens per frame
#define DI     64      // inter_channels CI
#define NTILE  36      // HW / 64 (proj/combine blocks, attn KEY tiles, attn q-blocks of 64)

typedef unsigned short u16;
typedef unsigned int   u32;
typedef __bf16   bf16x8 __attribute__((ext_vector_type(8)));
typedef _Float16 f16x8  __attribute__((ext_vector_type(8)));
typedef float    f32x4  __attribute__((ext_vector_type(4)));

__device__ __forceinline__ u16 f2bf_rne(float x) {
    union { float f; u32 u; } v; v.f = x;
    u32 r = (v.u + 0x7FFFu + ((v.u >> 16) & 1u)) >> 16;
    return (u16)r;
}
__device__ __forceinline__ u16 f2h(float x) {
    union { _Float16 h; u16 u; } c; c.h = (_Float16)x; return c.u;
}
__device__ __forceinline__ float bflo(u32 w) { union { u32 u; float f; } c; c.u = w << 16;         return c.f; }
__device__ __forceinline__ float bfhi(u32 w) { union { u32 u; float f; } c; c.u = w & 0xFFFF0000u; return c.f; }

// ---------------------------------------------------------------------------
// Kernel 1: q/k/v projection as one fp16 MFMA GEMM per 64-token block
// (validated round 7). q,k fp16 [n][p][d]; v bf16 TRANSPOSED [n][d][p].
// ---------------------------------------------------------------------------
__global__ __launch_bounds__(256) void proj_kernel(
    const float* __restrict__ F,
    const float* __restrict__ Wq, const float* __restrict__ bq,
    const float* __restrict__ Wk, const float* __restrict__ bk,
    const float* __restrict__ Wv, const float* __restrict__ bv,
    u16* __restrict__ qo, u16* __restrict__ ko, u16* __restrict__ vto)
{
    __shared__ __align__(16) u16 Wl[192 * 128];   // 49152 B fp16 [dout][c], swizzled
    __shared__ __align__(16) u16 Fl[64 * 128];    // 16384 B fp16 [tok][c], swizzled
    __shared__ __align__(16) u16 Vt[64 * 72];     //  9216 B bf16 v^T restage

    const int tid  = threadIdx.x;
    const int n    = blockIdx.x / NTILE;
    const int p0   = (blockIdx.x % NTILE) * 64;
    const int lane = tid & 63, wave = tid >> 6;
    const int lo   = lane & 15, hi = lane >> 4;

    // --- stage W (fp32 -> fp16): rows 0-63 Wq, 64-127 Wk, 128-191 Wv ---
    #pragma unroll
    for (int i = 0; i < 12; ++i) {
        int s = tid + i * 256;                    // chunk id 0..3071
        int row = s >> 4, ch = s & 15;
        const float* src = (row < 64)  ? &Wq[row * CCH]
                         : (row < 128) ? &Wk[(row - 64) * CCH]
                                       : &Wv[(row - 128) * CCH];
        float4 a = *(const float4*)&src[ch * 8];
        float4 b = *(const float4*)&src[ch * 8 + 4];
        union { u16 s8[8]; uint4 v; } pk;
        pk.s8[0] = f2h(a.x); pk.s8[1] = f2h(a.y); pk.s8[2] = f2h(a.z); pk.s8[3] = f2h(a.w);
        pk.s8[4] = f2h(b.x); pk.s8[5] = f2h(b.y); pk.s8[6] = f2h(b.z); pk.s8[7] = f2h(b.w);
        *(uint4*)&Wl[row * 128 + ((ch ^ (row & 15)) << 3)] = pk.v;
    }
    // --- stage F transposed [tok][c] (fp32 -> fp16), packed u32 writes ---
    const float* Fn = F + (size_t)n * CCH * HW;
    #pragma unroll
    for (int i = 0; i < 4; ++i) {
        int s  = tid + i * 256;                   // 0..1023
        int c0 = (s >> 4) * 2;                    // even channel
        int t0 = (s & 15) * 4;                    // token group
        const float* fp_ = &Fn[(size_t)c0 * HW + p0 + t0];
        float4 fa = *(const float4*)fp_;
        float4 fb = *(const float4*)(fp_ + HW);
        #pragma unroll
        for (int e = 0; e < 4; ++e) {
            int t = t0 + e;
            u32 w = (u32)f2h((&fa.x)[e]) | ((u32)f2h((&fb.x)[e]) << 16);
            *(u32*)&Fl[t * 128 + (((c0 >> 3) ^ (t & 15)) << 3) + (c0 & 7)] = w;
        }
    }
    __syncthreads();

    // --- A-frags: F rows = tokens wave*16 + lo ---
    const int arow = wave * 16 + lo;
    f16x8 af[4];
    #pragma unroll
    for (int ks = 0; ks < 4; ++ks)
        af[ks] = *(const f16x8*)&Fl[arow * 128 + (((ks * 4 + hi) ^ lo) << 3)];

    f32x4 acc[12];
    #pragma unroll
    for (int g = 0; g < 12; ++g)
        #pragma unroll
        for (int r = 0; r < 4; ++r) acc[g][r] = 0.f;

    #pragma unroll
    for (int g = 0; g < 12; ++g) {
        #pragma unroll
        for (int ks = 0; ks < 4; ++ks) {
            f16x8 bf = *(const f16x8*)&Wl[(g * 16 + lo) * 128 + (((ks * 4 + hi) ^ lo) << 3)];
            acc[g] = __builtin_amdgcn_mfma_f32_16x16x32_f16(af[ks], bf, acc[g], 0, 0, 0);
        }
    }

    // --- epilogue: D[row = token 4hi+r][col = dout g*16+lo] ---
    const int twb = p0 + wave * 16 + 4 * hi;      // + r = global token
    #pragma unroll
    for (int g = 0; g < 4; ++g) {
        float bQ = bq[g * 16 + lo], bK = bk[g * 16 + lo];
        #pragma unroll
        for (int r = 0; r < 4; ++r) {
            size_t off = ((size_t)n * HW + twb + r) * DI + g * 16 + lo;
            qo[off] = f2h(acc[g][r] + bQ);
            ko[off] = f2h(acc[g + 4][r] + bK);
        }
    }
    #pragma unroll
    for (int g = 0; g < 4; ++g) {
        float bV = bv[g * 16 + lo];
        #pragma unroll
        for (int r = 0; r < 4; ++r)
            Vt[(g * 16 + lo) * 72 + wave * 16 + 4 * hi + r] = f2bf_rne(acc[g + 8][r] + bV);
    }
    __syncthreads();
    #pragma unroll
    for (int i = 0; i < 2; ++i) {
        int s = tid + i * 256;                    // 0..511
        int d = s >> 3, c8 = (s & 7) * 8;
        *(uint4*)&vto[((size_t)n * DI + d) * HW + p0 + c8] = *(const uint4*)&Vt[d * 72 + c8];
    }
}

// ---------------------------------------------------------------------------
// Kernel 2: one-pass MFMA flash attention (no-max softmax), Q=32 rows/wave
// with A/B q-set frag sharing (validated round 7), now in 2-WAVE blocks
// (64 q-rows) so the grid is 1152 again (round-7 regression isolated to the
// grid-576 occupancy loss, not the Q=32 math).
// VALU diet: native __bf16 casts for P (compiler emits v_cvt_pk_bf16_f32),
// l accumulated from unrounded exps.
// K,V double-buffered in swizzled LDS, one barrier per tile.
// ---------------------------------------------------------------------------
__global__ __launch_bounds__(128, 3) void attn_pass_kernel(
    const u16* __restrict__ q, const u16* __restrict__ k, const u16* __restrict__ vt,
    u16* __restrict__ ypart)
{
    __shared__ __align__(16) u16 smem[16384];     // 32 KiB: K dbuf (fp16) | V dbuf (bf16)
    u16* const Kb0 = smem;
    u16* const Kb1 = smem + 4096;
    u16* const Vb0 = smem + 8192;
    u16* const Vb1 = smem + 12288;

    const int tid  = threadIdx.x;
    const int lane = tid & 63;
    const int wave = tid >> 6;                    // 0..1
    const int lo   = lane & 15, hi = lane >> 4;

    // chunked bijective XCD swizzle: 1152 = 8 * 144
    const int bid  = (int)blockIdx.x;
    const int w    = (bid & 7) * 144 + (bid >> 3);
    const int pass = w / (NBATCH * NTILE);
    const int rem  = w % (NBATCH * NTILE);
    const int n    = rem / NTILE;
    const int p0   = (rem % NTILE) * 64;

    const int nb = (pass == 0) ? (n > 0 ? n - 1 : 0)
                               : (n < NBATCH - 1 ? n + 1 : n);
    const u16* kp = k  + (size_t)nb * HW * DI;
    const u16* vp = vt + (size_t)nb * DI * HW;

    // Q fragments (B-operand of swapped QK), two 16-row sets per wave
    f16x8 qfA0, qfA1, qfB0, qfB1;
    {
        const u16* qp = q + ((size_t)n * HW + p0 + wave * 32 + lo) * DI + hi * 8;
        qfA0 = *(const f16x8*)qp;
        qfA1 = *(const f16x8*)(qp + 32);
        qfB0 = *(const f16x8*)(qp + 16 * DI);
        qfB1 = *(const f16x8*)(qp + 16 * DI + 32);
    }

    // staging: 128 threads x 4 rows x 16B cover each 8KB tile (K and V)
    const int sch = tid & 7;                      // 16B chunk in row
    const int sr  = tid >> 3;                     // 0..15
    int krow[4], koff[4], voff[4];
    #pragma unroll
    for (int j = 0; j < 4; ++j) {
        int row = sr + 16 * j;
        int fk  = (row & 3) | ((row & 8) >> 1);
        krow[j] = row;
        koff[j] = row * 64 + ((sch ^ fk) * 8);
        voff[j] = row * 64 + ((sch ^ (row & 7)) * 8);
    }

    // permuted K A-frag row base: kr_m = krbase + 4*(m&1) + 32*(m>>1)
    const int krbase = 8 * (lo >> 2) + (lo & 3);
    const int xl = lo & 7;

    f32x4 yaccA[4], yaccB[4];
    #pragma unroll
    for (int nf = 0; nf < 4; ++nf)
        #pragma unroll
        for (int r = 0; r < 4; ++r) { yaccA[nf][r] = 0.f; yaccB[nf][r] = 0.f; }
    float laccA = 0.f, laccB = 0.f;

    // prologue: tile0 -> buf0; tile1 -> regs
    uint4 ka[4], va[4];
    #pragma unroll
    for (int j = 0; j < 4; ++j) {
        ka[j] = *(const uint4*)(kp + (size_t)krow[j] * DI + sch * 8);
        va[j] = *(const uint4*)(vp + (size_t)krow[j] * HW + sch * 8);
    }
    #pragma unroll
    for (int j = 0; j < 4; ++j) {
        *(uint4*)&Kb0[koff[j]] = ka[j];
        *(uint4*)&Vb0[voff[j]] = va[j];
    }
    #pragma unroll
    for (int j = 0; j < 4; ++j) {
        ka[j] = *(const uint4*)(kp + (size_t)(64 + krow[j]) * DI + sch * 8);
        va[j] = *(const uint4*)(vp + (size_t)krow[j] * HW + 64 + sch * 8);
    }
    __syncthreads();

    auto body = [&](int t, const u16* Kc, const u16* Vc, u16* Kn, u16* Vn) {
        // --- swapped QK^T with permuted A rows (both q-sets share K frags) ---
        f32x4 stA[4], stB[4];
        __builtin_amdgcn_s_setprio(1);
        #pragma unroll
        for (int m = 0; m < 4; ++m) {
            const int kr = krbase + 4 * (m & 1) + 32 * (m >> 1);
            f16x8 a0 = *(const f16x8*)&Kc[kr * 64 + ((hi ^ xl) * 8)];
            f16x8 a1 = *(const f16x8*)&Kc[kr * 64 + (((4 + hi) ^ xl) * 8)];
            f32x4 zA = {0.f, 0.f, 0.f, 0.f};
            zA = __builtin_amdgcn_mfma_f32_16x16x32_f16(a0, qfA0, zA, 0, 0, 0);
            zA = __builtin_amdgcn_mfma_f32_16x16x32_f16(a1, qfA1, zA, 0, 0, 0);
            stA[m] = zA;
            f32x4 zB = {0.f, 0.f, 0.f, 0.f};
            zB = __builtin_amdgcn_mfma_f32_16x16x32_f16(a0, qfB0, zB, 0, 0, 0);
            zB = __builtin_amdgcn_mfma_f32_16x16x32_f16(a1, qfB1, zB, 0, 0, 0);
            stB[m] = zB;
        }
        __builtin_amdgcn_s_setprio(0);

        // --- P = exp(S) -> bf16 via native casts (compiler packs);
        //     l accumulated from the unrounded exps ---
        bf16x8 paA0, paA1, paB0, paB1;
        #pragma unroll
        for (int m = 0; m < 4; ++m) {
            float e0 = __expf(stA[m][0]);
            float e1 = __expf(stA[m][1]);
            float e2 = __expf(stA[m][2]);
            float e3 = __expf(stA[m][3]);
            laccA += (e0 + e1) + (e2 + e3);
            __bf16 b0 = (__bf16)e0, b1 = (__bf16)e1, b2 = (__bf16)e2, b3 = (__bf16)e3;
            if (m == 0)      { paA0[0] = b0; paA0[1] = b1; paA0[2] = b2; paA0[3] = b3; }
            else if (m == 1) { paA0[4] = b0; paA0[5] = b1; paA0[6] = b2; paA0[7] = b3; }
            else if (m == 2) { paA1[0] = b0; paA1[1] = b1; paA1[2] = b2; paA1[3] = b3; }
            else             { paA1[4] = b0; paA1[5] = b1; paA1[6] = b2; paA1[7] = b3; }
        }
        #pragma unroll
        for (int m = 0; m < 4; ++m) {
            float e0 = __expf(stB[m][0]);
            float e1 = __expf(stB[m][1]);
            float e2 = __expf(stB[m][2]);
            float e3 = __expf(stB[m][3]);
            laccB += (e0 + e1) + (e2 + e3);
            __bf16 b0 = (__bf16)e0, b1 = (__bf16)e1, b2 = (__bf16)e2, b3 = (__bf16)e3;
            if (m == 0)      { paB0[0] = b0; paB0[1] = b1; paB0[2] = b2; paB0[3] = b3; }
            else if (m == 1) { paB0[4] = b0; paB0[5] = b1; paB0[6] = b2; paB0[7] = b3; }
            else if (m == 2) { paB1[0] = b0; paB1[1] = b1; paB1[2] = b2; paB1[3] = b3; }
            else             { paB1[4] = b0; paB1[5] = b1; paB1[6] = b2; paB1[7] = b3; }
        }

        // --- PV: both q-sets share V frags ---
        __builtin_amdgcn_s_setprio(1);
        #pragma unroll
        for (int nf = 0; nf < 4; ++nf) {
            const int vr = nf * 16 + lo;
            bf16x8 v0 = *(const bf16x8*)&Vc[vr * 64 + ((hi ^ xl) * 8)];
            bf16x8 v1 = *(const bf16x8*)&Vc[vr * 64 + (((4 + hi) ^ xl) * 8)];
            yaccA[nf] = __builtin_amdgcn_mfma_f32_16x16x32_bf16(paA0, v0, yaccA[nf], 0, 0, 0);
            yaccA[nf] = __builtin_amdgcn_mfma_f32_16x16x32_bf16(paA1, v1, yaccA[nf], 0, 0, 0);
            yaccB[nf] = __builtin_amdgcn_mfma_f32_16x16x32_bf16(paB0, v0, yaccB[nf], 0, 0, 0);
            yaccB[nf] = __builtin_amdgcn_mfma_f32_16x16x32_bf16(paB1, v1, yaccB[nf], 0, 0, 0);
        }
        __builtin_amdgcn_s_setprio(0);

        // --- stage tile t+1; prefetch t+2 ---
        if (t + 1 < NTILE) {
            #pragma unroll
            for (int j = 0; j < 4; ++j) {
                *(uint4*)&Kn[koff[j]] = ka[j];
                *(uint4*)&Vn[voff[j]] = va[j];
            }
        }
        if (t + 2 < NTILE) {
            int tb = (t + 2) * 64;
            #pragma unroll
            for (int j = 0; j < 4; ++j) {
                ka[j] = *(const uint4*)(kp + (size_t)(tb + krow[j]) * DI + sch * 8);
                va[j] = *(const uint4*)(vp + (size_t)krow[j] * HW + tb + sch * 8);
            }
        }
        __syncthreads();
    };

    #pragma unroll 1
    for (int tt = 0; tt < NTILE; tt += 2) {
        body(tt,     Kb0, Vb0, Kb1, Vb1);
        body(tt + 1, Kb1, Vb1, Kb0, Vb0);
    }

    // --- finalize (per set): reduce l over hi-groups, per-row inv ---
    float lA = laccA;
    lA += __shfl_xor(lA, 16);
    lA += __shfl_xor(lA, 32);
    float invA = 1.f / lA;
    float lB = laccB;
    lB += __shfl_xor(lB, 16);
    lB += __shfl_xor(lB, 32);
    float invB = 1.f / lB;
    float invqA[4], invqB[4];
    #pragma unroll
    for (int r = 0; r < 4; ++r) {
        invqA[r] = __shfl(invA, 20 * hi + r);     // q = 4hi+r (set A)
        invqB[r] = __shfl(invB, 20 * hi + r);
    }

    __syncthreads();                              // done with K/V buffers
    u16* yw = smem;                               // [64][72] bf16 restage
    #pragma unroll
    for (int nf = 0; nf < 4; ++nf)
        #pragma unroll
        for (int r = 0; r < 4; ++r) {
            yw[(wave * 32 + 4 * hi + r) * 72 + nf * 16 + lo]      = f2bf_rne(yaccA[nf][r] * invqA[r]);
            yw[(wave * 32 + 16 + 4 * hi + r) * 72 + nf * 16 + lo] = f2bf_rne(yaccB[nf][r] * invqB[r]);
        }
    __syncthreads();

    u16* yg = ypart + ((size_t)(pass * NBATCH + n) * HW + p0) * DI;
    #pragma unroll
    for (int s4 = 0; s4 < 4; ++s4) {
        int idx = tid + s4 * 128;                 // 512 x 16B chunks (64 rows)
        int row = idx >> 3, c8 = (idx & 7) * 8;
        *(uint4*)&yg[row * DI + c8] = *(const uint4*)&yw[row * 72 + c8];
    }
}

// ---------------------------------------------------------------------------
// Kernel 3: combine passes + fused z-projection + residual.
// z = (y_b + y_a) @ Wz^T + 2*bz + F                     (validated round 3)
// ---------------------------------------------------------------------------
__global__ __launch_bounds__(256) void combine_kernel(
    const u16* __restrict__ ypart, const float* __restrict__ Wz,
    const float* __restrict__ bz, const float* __restrict__ F,
    float* __restrict__ out)
{
    __shared__ __align__(16) float ys[64 * 68];
    const int tid = threadIdx.x;
    const int n   = blockIdx.x / NTILE;
    const int p0  = (blockIdx.x % NTILE) * 64;
    const u16* y0 = ypart + ((size_t)n * HW + p0) * DI;
    const u16* y1 = ypart + ((size_t)(NBATCH + n) * HW + p0) * DI;

    #pragma unroll
    for (int s = 0; s < 2; ++s) {
        int idx = tid + s * 256;
        int row = idx >> 3, c8 = (idx & 7) * 8;
        uint4 a = *(const uint4*)&y0[row * DI + c8];
        uint4 b = *(const uint4*)&y1[row * DI + c8];
        const u32 au[4] = {a.x, a.y, a.z, a.w};
        const u32 bu[4] = {b.x, b.y, b.z, b.w};
        float* d = &ys[row * 68 + c8];
        #pragma unroll
        for (int e = 0; e < 4; ++e) {
            d[e * 2]     = bflo(au[e]) + bflo(bu[e]);
            d[e * 2 + 1] = bfhi(au[e]) + bfhi(bu[e]);
        }
    }
    __syncthreads();

    const int lane = tid & 63;
    const int wave = tid >> 6;
    float acc[32];
    #pragma unroll
    for (int i = 0; i < 32; ++i) acc[i] = 0.f;
    #pragma unroll
    for (int d4 = 0; d4 < 16; ++d4) {
        float4 yy = *(const float4*)&ys[lane * 68 + d4 * 4];
        #pragma unroll 8
        for (int i = 0; i < 32; ++i) {
            int c = wave + 4 * i;                  // wave-uniform -> scalar Wz loads
            float4 ww = *(const float4*)&Wz[c * DI + d4 * 4];
            acc[i] += yy.x * ww.x + yy.y * ww.y + yy.z * ww.z + yy.w * ww.w;
        }
    }
    #pragma unroll 4
    for (int i = 0; i < 32; ++i) {
        int c = wave + 4 * i;
        size_t gi = (size_t)(n * CCH + c) * HW + p0 + lane;
        out[gi] = acc[i] + 2.f * bz[c] + F[gi];    // coalesced store + residual
    }
}

extern "C" void kernel_launch(void* const* d_in, const int* in_sizes, int n_in,
                              void* d_out, int out_size, void* d_ws, size_t ws_size,
                              hipStream_t stream) {
    const float* F  = (const float*)d_in[0];
    const float* Wq = (const float*)d_in[1];
    const float* bq = (const float*)d_in[2];
    const float* Wk = (const float*)d_in[3];
    const float* bk = (const float*)d_in[4];
    const float* Wv = (const float*)d_in[5];
    const float* bv = (const float*)d_in[6];
    const float* Wz = (const float*)d_in[7];
    const float* bz = (const float*)d_in[8];
    float* outp = (float*)d_out;

    const size_t tok = (size_t)NBATCH * HW * DI;   // 2,359,296 elements
    u16* qb  = (u16*)d_ws;                         // fp16
    u16* kb  = qb  + tok;                          // fp16
    u16* vtb = kb  + tok;                          // bf16, transposed
    u16* yp  = vtb + tok;                          // 2*tok bf16 partials
    // total ws: 5 * tok * 2B = 23.6 MB

    proj_kernel<<<NBATCH * NTILE, 256, 0, stream>>>(F, Wq, bq, Wk, bk, Wv, bv, qb, kb, vtb);
    attn_pass_kernel<<<2 * NBATCH * NTILE, 128, 0, stream>>>(qb, kb, vtb, yp);
    combine_kernel<<<NBATCH * NTILE, 256, 0, stream>>>(yp, Wz, bz, F, outp);
}

// Round 9
// 155.271 us; speedup vs baseline: 2.1902x; 2.1902x over previous
//
#include <hip/hip_runtime.h>
#include <math.h>

// Problem constants (fixed by the reference)
#define NBATCH 16
#define CCH    128     // channels C
#define HW     2304    // 48*48 tokens per frame
#define DI     64      // inter_channels CI
#define NTILE  36      // HW / 64

typedef unsigned short u16;
typedef unsigned int   u32;
typedef __bf16   bf16x8 __attribute__((ext_vector_type(8)));
typedef _Float16 f16x8  __attribute__((ext_vector_type(8)));
typedef float    f32x4  __attribute__((ext_vector_type(4)));

__device__ __forceinline__ u16 f2bf_rne(float x) {
    union { float f; u32 u; } v; v.f = x;
    u32 r = (v.u + 0x7FFFu + ((v.u >> 16) & 1u)) >> 16;
    return (u16)r;
}
__device__ __forceinline__ u16 f2h(float x) {
    union { _Float16 h; u16 u; } c; c.h = (_Float16)x; return c.u;
}
__device__ __forceinline__ float bflo(u32 w) { union { u32 u; float f; } c; c.u = w << 16;         return c.f; }
__device__ __forceinline__ float bfhi(u32 w) { union { u32 u; float f; } c; c.u = w & 0xFFFF0000u; return c.f; }

// ---------------------------------------------------------------------------
// Kernel 0: one-time W -> fp16 conversion in MFMA B-frag order:
// Wf[((g*4+ks)*64 + lane)*8 + j] = Wrow[g*16+lo][(ks*4+hi)*8 + j]
// (rows 0-63 Wq, 64-127 Wk, 128-191 Wv). 49 KB total -> L2-resident;
// lets proj_kernel read W-frags directly from global (coalesced 1KB/inst)
// and drop its 49 KB W LDS buffer (round-8 attribution: proj was
// 2 blocks/CU occupancy-capped by 75 KB LDS).
// ---------------------------------------------------------------------------
__global__ __launch_bounds__(256) void wprep_kernel(
    const float* __restrict__ Wq, const float* __restrict__ Wk,
    const float* __restrict__ Wv, u16* __restrict__ Wf)
{
    const int idx  = blockIdx.x * 256 + threadIdx.x;   // 0..3071
    const int lane = idx & 63;
    const int fi   = idx >> 6;                         // g*4+ks, 0..47
    const int g = fi >> 2, ks = fi & 3;
    const int lo = lane & 15, hi = lane >> 4;
    const int row = g * 16 + lo;                       // 0..191
    const float* src = (row < 64)  ? &Wq[row * CCH]
                     : (row < 128) ? &Wk[(row - 64) * CCH]
                                   : &Wv[(row - 128) * CCH];
    const int c0 = (ks * 4 + hi) * 8;
    float4 a = *(const float4*)&src[c0];
    float4 b = *(const float4*)&src[c0 + 4];
    union { u16 s8[8]; uint4 v; } pk;
    pk.s8[0] = f2h(a.x); pk.s8[1] = f2h(a.y); pk.s8[2] = f2h(a.z); pk.s8[3] = f2h(a.w);
    pk.s8[4] = f2h(b.x); pk.s8[5] = f2h(b.y); pk.s8[6] = f2h(b.z); pk.s8[7] = f2h(b.w);
    *(uint4*)&Wf[(size_t)idx * 8] = pk.v;
}

// ---------------------------------------------------------------------------
// Kernel 1: q/k/v projection as one fp16 MFMA GEMM per 64-token block
// (math validated round 7). W-frags read directly from global (L2);
// LDS only F-tile (16 KB) + v^T restage (9 KB) -> 6 blocks/CU.
// q,k fp16 [n][p][d]; v bf16 TRANSPOSED [n][d][p].
// ---------------------------------------------------------------------------
__global__ __launch_bounds__(256) void proj_kernel(
    const float* __restrict__ F, const u16* __restrict__ Wf,
    const float* __restrict__ bq, const float* __restrict__ bk,
    const float* __restrict__ bv,
    u16* __restrict__ qo, u16* __restrict__ ko, u16* __restrict__ vto)
{
    __shared__ __align__(16) u16 Fl[64 * 128];    // 16384 B fp16 [tok][c], swizzled
    __shared__ __align__(16) u16 Vt[64 * 72];     //  9216 B bf16 v^T restage

    const int tid  = threadIdx.x;
    const int n    = blockIdx.x / NTILE;
    const int p0   = (blockIdx.x % NTILE) * 64;
    const int lane = tid & 63, wave = tid >> 6;
    const int lo   = lane & 15, hi = lane >> 4;

    // --- stage F transposed [tok][c] (fp32 -> fp16), packed u32 writes ---
    const float* Fn = F + (size_t)n * CCH * HW;
    #pragma unroll
    for (int i = 0; i < 4; ++i) {
        int s  = tid + i * 256;                   // 0..1023
        int c0 = (s >> 4) * 2;                    // even channel
        int t0 = (s & 15) * 4;                    // token group
        const float* fp_ = &Fn[(size_t)c0 * HW + p0 + t0];
        float4 fa = *(const float4*)fp_;
        float4 fb = *(const float4*)(fp_ + HW);
        #pragma unroll
        for (int e = 0; e < 4; ++e) {
            int t = t0 + e;
            u32 w = (u32)f2h((&fa.x)[e]) | ((u32)f2h((&fb.x)[e]) << 16);
            *(u32*)&Fl[t * 128 + (((c0 >> 3) ^ (t & 15)) << 3) + (c0 & 7)] = w;
        }
    }
    __syncthreads();

    // --- A-frags: F rows = tokens wave*16 + lo ---
    const int arow = wave * 16 + lo;
    f16x8 af[4];
    #pragma unroll
    for (int ks = 0; ks < 4; ++ks)
        af[ks] = *(const f16x8*)&Fl[arow * 128 + (((ks * 4 + hi) ^ lo) << 3)];

    f32x4 acc[12];
    #pragma unroll
    for (int g = 0; g < 12; ++g)
        #pragma unroll
        for (int r = 0; r < 4; ++r) acc[g][r] = 0.f;

    #pragma unroll
    for (int g = 0; g < 12; ++g) {
        #pragma unroll
        for (int ks = 0; ks < 4; ++ks) {
            f16x8 bf = *(const f16x8*)&Wf[(size_t)((g * 4 + ks) * 64 + lane) * 8];
            acc[g] = __builtin_amdgcn_mfma_f32_16x16x32_f16(af[ks], bf, acc[g], 0, 0, 0);
        }
    }

    // --- epilogue: D[row = token 4hi+r][col = dout g*16+lo] ---
    const int twb = p0 + wave * 16 + 4 * hi;      // + r = global token
    #pragma unroll
    for (int g = 0; g < 4; ++g) {
        float bQ = bq[g * 16 + lo], bK = bk[g * 16 + lo];
        #pragma unroll
        for (int r = 0; r < 4; ++r) {
            size_t off = ((size_t)n * HW + twb + r) * DI + g * 16 + lo;
            qo[off] = f2h(acc[g][r] + bQ);
            ko[off] = f2h(acc[g + 4][r] + bK);
        }
    }
    #pragma unroll
    for (int g = 0; g < 4; ++g) {
        float bV = bv[g * 16 + lo];
        #pragma unroll
        for (int r = 0; r < 4; ++r)
            Vt[(g * 16 + lo) * 72 + wave * 16 + 4 * hi + r] = f2bf_rne(acc[g + 8][r] + bV);
    }
    __syncthreads();
    #pragma unroll
    for (int i = 0; i < 2; ++i) {
        int s = tid + i * 256;                    // 0..511
        int d = s >> 3, c8 = (s & 7) * 8;
        *(uint4*)&vto[((size_t)n * DI + d) * HW + p0 + c8] = *(const uint4*)&Vt[d * 72 + c8];
    }
}

// ---------------------------------------------------------------------------
// Kernel 2: one-pass MFMA flash attention (no-max softmax) — EXACT round-6
// structure (256 thr, 4 waves, Q=16/wave, grid 1152, K/V dbuf in swizzled
// LDS, 1 barrier/tile, κ-permuted K A-frag rows) with two validated deltas:
// fp16 QK^T and native __bf16 P casts (compiler packs), l from unrounded exps.
// ---------------------------------------------------------------------------
__global__ __launch_bounds__(256, 4) void attn_pass_kernel(
    const u16* __restrict__ q, const u16* __restrict__ k, const u16* __restrict__ vt,
    u16* __restrict__ ypart)
{
    __shared__ __align__(16) u16 smem[16384];     // 32 KiB: K dbuf (fp16) | V dbuf (bf16)
    u16* const Kb0 = smem;
    u16* const Kb1 = smem + 4096;
    u16* const Vb0 = smem + 8192;
    u16* const Vb1 = smem + 12288;

    const int tid  = threadIdx.x;
    const int lane = tid & 63;
    const int wave = tid >> 6;
    const int lo   = lane & 15, hi = lane >> 4;

    // chunked bijective XCD swizzle: 1152 = 8 * 144
    const int bid  = (int)blockIdx.x;
    const int w    = (bid & 7) * 144 + (bid >> 3);
    const int pass = w / (NBATCH * NTILE);
    const int rem  = w % (NBATCH * NTILE);
    const int n    = rem / NTILE;
    const int p0   = (rem % NTILE) * 64;

    const int nb = (pass == 0) ? (n > 0 ? n - 1 : 0)
                               : (n < NBATCH - 1 ? n + 1 : n);
    const u16* kp = k  + (size_t)nb * HW * DI;
    const u16* vp = vt + (size_t)nb * DI * HW;

    // Q fragments (B-operand of swapped QK): lane holds Q[q=lo][d=hi*8+j]
    f16x8 qf0, qf1;
    {
        const u16* qp = q + ((size_t)n * HW + p0 + wave * 16 + lo) * DI + hi * 8;
        qf0 = *(const f16x8*)qp;
        qf1 = *(const f16x8*)(qp + 32);
    }

    // staging geometry: 512 x 16B chunks per 8KB tile; thread covers 2 rows
    const int sch   = tid & 7;
    const int srow0 = tid >> 3;
    const int srow1 = srow0 + 32;
    const int fk0   = (srow0 & 3) | ((srow0 & 8) >> 1);
    const int fk1   = (srow1 & 3) | ((srow1 & 8) >> 1);
    const int koff0 = srow0 * 64 + ((sch ^ fk0) * 8);
    const int koff1 = srow1 * 64 + ((sch ^ fk1) * 8);
    const int voff0 = srow0 * 64 + ((sch ^ (srow0 & 7)) * 8);
    const int voff1 = srow1 * 64 + ((sch ^ (srow1 & 7)) * 8);

    // permuted K A-frag row base: kr_m = krbase + 4*(m&1) + 32*(m>>1)
    const int krbase = 8 * (lo >> 2) + (lo & 3);
    const int xl = lo & 7;

    f32x4 yacc[4];
    #pragma unroll
    for (int nf = 0; nf < 4; ++nf)
        #pragma unroll
        for (int r = 0; r < 4; ++r) yacc[nf][r] = 0.f;
    float lacc = 0.f;

    // prologue: tile0 -> buf0; tile1 -> regs
    uint4 ka0 = *(const uint4*)(kp + (size_t)srow0 * DI + sch * 8);
    uint4 ka1 = *(const uint4*)(kp + (size_t)srow1 * DI + sch * 8);
    uint4 va0 = *(const uint4*)(vp + (size_t)srow0 * HW + sch * 8);
    uint4 va1 = *(const uint4*)(vp + (size_t)srow1 * HW + sch * 8);
    *(uint4*)&Kb0[koff0] = ka0;  *(uint4*)&Kb0[koff1] = ka1;
    *(uint4*)&Vb0[voff0] = va0;  *(uint4*)&Vb0[voff1] = va1;
    ka0 = *(const uint4*)(kp + (size_t)(64 + srow0) * DI + sch * 8);
    ka1 = *(const uint4*)(kp + (size_t)(64 + srow1) * DI + sch * 8);
    va0 = *(const uint4*)(vp + (size_t)srow0 * HW + 64 + sch * 8);
    va1 = *(const uint4*)(vp + (size_t)srow1 * HW + 64 + sch * 8);
    __syncthreads();

    auto body = [&](int t, const u16* Kc, const u16* Vc, u16* Kn, u16* Vn) {
        // --- swapped QK^T with permuted A rows ---
        // st[m][r] = S[key = 8hi + 4(m&1) + r + 32(m>>1)][q = lo]
        f32x4 st[4];
        __builtin_amdgcn_s_setprio(1);
        #pragma unroll
        for (int m = 0; m < 4; ++m) {
            const int kr = krbase + 4 * (m & 1) + 32 * (m >> 1);
            f16x8 a0 = *(const f16x8*)&Kc[kr * 64 + ((hi ^ xl) * 8)];
            f16x8 a1 = *(const f16x8*)&Kc[kr * 64 + (((4 + hi) ^ xl) * 8)];
            f32x4 z = {0.f, 0.f, 0.f, 0.f};
            z = __builtin_amdgcn_mfma_f32_16x16x32_f16(a0, qf0, z, 0, 0, 0);
            z = __builtin_amdgcn_mfma_f32_16x16x32_f16(a1, qf1, z, 0, 0, 0);
            st[m] = z;
        }
        __builtin_amdgcn_s_setprio(0);

        // --- P = exp(S) -> bf16 via native casts (compiler emits cvt_pk);
        //     l accumulated from the unrounded exps ---
        bf16x8 pa0, pa1;
        #pragma unroll
        for (int m = 0; m < 4; ++m) {
            float e0 = __expf(st[m][0]);
            float e1 = __expf(st[m][1]);
            float e2 = __expf(st[m][2]);
            float e3 = __expf(st[m][3]);
            lacc += (e0 + e1) + (e2 + e3);
            __bf16 b0 = (__bf16)e0, b1 = (__bf16)e1, b2 = (__bf16)e2, b3 = (__bf16)e3;
            if (m == 0)      { pa0[0] = b0; pa0[1] = b1; pa0[2] = b2; pa0[3] = b3; }
            else if (m == 1) { pa0[4] = b0; pa0[5] = b1; pa0[6] = b2; pa0[7] = b3; }
            else if (m == 2) { pa1[0] = b0; pa1[1] = b1; pa1[2] = b2; pa1[3] = b3; }
            else             { pa1[4] = b0; pa1[5] = b1; pa1[6] = b2; pa1[7] = b3; }
        }

        // --- PV: Y[q][d] += P(16x64) x V(64k x 64d)  (B from V^T tile) ---
        __builtin_amdgcn_s_setprio(1);
        #pragma unroll
        for (int nf = 0; nf < 4; ++nf) {
            const int vr = nf * 16 + lo;
            bf16x8 v0 = *(const bf16x8*)&Vc[vr * 64 + ((hi ^ xl) * 8)];
            bf16x8 v1 = *(const bf16x8*)&Vc[vr * 64 + (((4 + hi) ^ xl) * 8)];
            yacc[nf] = __builtin_amdgcn_mfma_f32_16x16x32_bf16(pa0, v0, yacc[nf], 0, 0, 0);
            yacc[nf] = __builtin_amdgcn_mfma_f32_16x16x32_bf16(pa1, v1, yacc[nf], 0, 0, 0);
        }
        __builtin_amdgcn_s_setprio(0);

        // --- stage tile t+1 into the other buffer; prefetch t+2 ---
        if (t + 1 < NTILE) {
            *(uint4*)&Kn[koff0] = ka0; *(uint4*)&Kn[koff1] = ka1;
            *(uint4*)&Vn[voff0] = va0; *(uint4*)&Vn[voff1] = va1;
        }
        if (t + 2 < NTILE) {
            int tb = (t + 2) * 64;
            ka0 = *(const uint4*)(kp + (size_t)(tb + srow0) * DI + sch * 8);
            ka1 = *(const uint4*)(kp + (size_t)(tb + srow1) * DI + sch * 8);
            va0 = *(const uint4*)(vp + (size_t)srow0 * HW + tb + sch * 8);
            va1 = *(const uint4*)(vp + (size_t)srow1 * HW + tb + sch * 8);
        }
        __syncthreads();
    };

    #pragma unroll 1
    for (int tt = 0; tt < NTILE; tt += 2) {
        body(tt,     Kb0, Vb0, Kb1, Vb1);
        body(tt + 1, Kb1, Vb1, Kb0, Vb0);
    }

    // --- finalize: per-lane lacc covers keys {8hi..8hi+7, 32+8hi..} at q=lo;
    //     reduce over the hi dimension -> full l(q=lo) ---
    float l = lacc;
    l += __shfl_xor(l, 16);
    l += __shfl_xor(l, 32);
    float inv = 1.f / l;                       // valid for q = lo at every lane
    float invq[4];
    #pragma unroll
    for (int r = 0; r < 4; ++r) invq[r] = __shfl(inv, 20 * hi + r);  // q = 4hi+r

    __syncthreads();                           // done with K/V buffers
    u16* yw = smem;                            // [64][72] bf16 restage
    #pragma unroll
    for (int nf = 0; nf < 4; ++nf)
        #pragma unroll
        for (int r = 0; r < 4; ++r)
            yw[(wave * 16 + hi * 4 + r) * 72 + nf * 16 + lo] =
                f2bf_rne(yacc[nf][r] * invq[r]);
    __syncthreads();

    u16* yg = ypart + ((size_t)(pass * NBATCH + n) * HW + p0) * DI;
    #pragma unroll
    for (int s = 0; s < 2; ++s) {
        int idx = tid + s * 256;
        int row = idx >> 3, c8 = (idx & 7) * 8;
        *(uint4*)&yg[row * DI + c8] = *(const uint4*)&yw[row * 72 + c8];
    }
}

// ---------------------------------------------------------------------------
// Kernel 3: combine passes + fused z-projection + residual.
// z = (y_b + y_a) @ Wz^T + 2*bz + F                     (validated round 3)
// ---------------------------------------------------------------------------
__global__ __launch_bounds__(256) void combine_kernel(
    const u16* __restrict__ ypart, const float* __restrict__ Wz,
    const float* __restrict__ bz, const float* __restrict__ F,
    float* __restrict__ out)
{
    __shared__ __align__(16) float ys[64 * 68];
    const int tid = threadIdx.x;
    const int n   = blockIdx.x / NTILE;
    const int p0  = (blockIdx.x % NTILE) * 64;
    const u16* y0 = ypart + ((size_t)n * HW + p0) * DI;
    const u16* y1 = ypart + ((size_t)(NBATCH + n) * HW + p0) * DI;

    #pragma unroll
    for (int s = 0; s < 2; ++s) {
        int idx = tid + s * 256;
        int row = idx >> 3, c8 = (idx & 7) * 8;
        uint4 a = *(const uint4*)&y0[row * DI + c8];
        uint4 b = *(const uint4*)&y1[row * DI + c8];
        const u32 au[4] = {a.x, a.y, a.z, a.w};
        const u32 bu[4] = {b.x, b.y, b.z, b.w};
        float* d = &ys[row * 68 + c8];
        #pragma unroll
        for (int e = 0; e < 4; ++e) {
            d[e * 2]     = bflo(au[e]) + bflo(bu[e]);
            d[e * 2 + 1] = bfhi(au[e]) + bfhi(bu[e]);
        }
    }
    __syncthreads();

    const int lane = tid & 63;
    const int wave = tid >> 6;
    float acc[32];
    #pragma unroll
    for (int i = 0; i < 32; ++i) acc[i] = 0.f;
    #pragma unroll
    for (int d4 = 0; d4 < 16; ++d4) {
        float4 yy = *(const float4*)&ys[lane * 68 + d4 * 4];
        #pragma unroll 8
        for (int i = 0; i < 32; ++i) {
            int c = wave + 4 * i;                  // wave-uniform -> scalar Wz loads
            float4 ww = *(const float4*)&Wz[c * DI + d4 * 4];
            acc[i] += yy.x * ww.x + yy.y * ww.y + yy.z * ww.z + yy.w * ww.w;
        }
    }
    #pragma unroll 4
    for (int i = 0; i < 32; ++i) {
        int c = wave + 4 * i;
        size_t gi = (size_t)(n * CCH + c) * HW + p0 + lane;
        out[gi] = acc[i] + 2.f * bz[c] + F[gi];    // coalesced store + residual
    }
}

extern "C" void kernel_launch(void* const* d_in, const int* in_sizes, int n_in,
                              void* d_out, int out_size, void* d_ws, size_t ws_size,
                              hipStream_t stream) {
    const float* F  = (const float*)d_in[0];
    const float* Wq = (const float*)d_in[1];
    const float* bq = (const float*)d_in[2];
    const float* Wk = (const float*)d_in[3];
    const float* bk = (const float*)d_in[4];
    const float* Wv = (const float*)d_in[5];
    const float* bv = (const float*)d_in[6];
    const float* Wz = (const float*)d_in[7];
    const float* bz = (const float*)d_in[8];
    float* outp = (float*)d_out;

    const size_t tok = (size_t)NBATCH * HW * DI;   // 2,359,296 elements
    u16* qb  = (u16*)d_ws;                         // fp16
    u16* kb  = qb  + tok;                          // fp16
    u16* vtb = kb  + tok;                          // bf16, transposed
    u16* yp  = vtb + tok;                          // 2*tok bf16 partials
    u16* wf  = yp  + 2 * tok;                      // 24576 fp16 frag-ordered W
    // total ws: (5*tok + 24576) * 2B ~= 23.65 MB

    wprep_kernel<<<12, 256, 0, stream>>>(Wq, Wk, Wv, wf);
    proj_kernel<<<NBATCH * NTILE, 256, 0, stream>>>(F, wf, bq, bk, bv, qb, kb, vtb);
    attn_pass_kernel<<<2 * NBATCH * NTILE, 256, 0, stream>>>(qb, kb, vtb, yp);
    combine_kernel<<<NBATCH * NTILE, 256, 0, stream>>>(yp, Wz, bz, F, outp);
}

// Round 10
// 97.610 us; speedup vs baseline: 3.4840x; 1.5907x over previous
//
#include <hip/hip_runtime.h>
#include <math.h>

// Problem constants (fixed by the reference)
#define NBATCH 16
#define CCH    128     // channels C
#define HW     2304    // 48*48 tokens per frame
#define DI     64      // inter_channels CI
#define NTILE  36      // HW / 64

typedef unsigned short u16;
typedef unsigned int   u32;
typedef __bf16   bf16x8 __attribute__((ext_vector_type(8)));
typedef _Float16 f16x8  __attribute__((ext_vector_type(8)));
typedef float    f32x4  __attribute__((ext_vector_type(4)));

__device__ __forceinline__ u16 f2bf_rne(float x) {
    union { float f; u32 u; } v; v.f = x;
    u32 r = (v.u + 0x7FFFu + ((v.u >> 16) & 1u)) >> 16;
    return (u16)r;
}
__device__ __forceinline__ u16 f2h(float x) {
    union { _Float16 h; u16 u; } c; c.h = (_Float16)x; return c.u;
}

// ---------------------------------------------------------------------------
// Kernel 0: one-time W -> fp16 conversion in MFMA B-frag order.
// idx 0..3071  : Wq/Wk/Wv -> Wf  (48 frag-sets of K=32; validated round 9)
// idx 3072..4095: Wz -> Wzf (16 frag-sets: g=0..7 channel groups, ks=0..1)
//   Wzf[((g*2+ks)*64+lane)*8+j] = Wz[g*16+lo][ks*32+hi*8+j]
// ---------------------------------------------------------------------------
__global__ __launch_bounds__(256) void wprep_kernel(
    const float* __restrict__ Wq, const float* __restrict__ Wk,
    const float* __restrict__ Wv, const float* __restrict__ Wz,
    u16* __restrict__ Wf, u16* __restrict__ Wzf)
{
    const int idx  = blockIdx.x * 256 + threadIdx.x;   // 0..4095
    if (idx < 3072) {
        const int lane = idx & 63;
        const int fi   = idx >> 6;                     // g*4+ks, 0..47
        const int g = fi >> 2, ks = fi & 3;
        const int lo = lane & 15, hi = lane >> 4;
        const int row = g * 16 + lo;                   // 0..191
        const float* src = (row < 64)  ? &Wq[row * CCH]
                         : (row < 128) ? &Wk[(row - 64) * CCH]
                                       : &Wv[(row - 128) * CCH];
        const int c0 = (ks * 4 + hi) * 8;
        float4 a = *(const float4*)&src[c0];
        float4 b = *(const float4*)&src[c0 + 4];
        union { u16 s8[8]; uint4 v; } pk;
        pk.s8[0] = f2h(a.x); pk.s8[1] = f2h(a.y); pk.s8[2] = f2h(a.z); pk.s8[3] = f2h(a.w);
        pk.s8[4] = f2h(b.x); pk.s8[5] = f2h(b.y); pk.s8[6] = f2h(b.z); pk.s8[7] = f2h(b.w);
        *(uint4*)&Wf[(size_t)idx * 8] = pk.v;
    } else {
        const int t    = idx - 3072;                   // 0..1023
        const int lane = t & 63;
        const int fi   = t >> 6;                       // g*2+ks, 0..15
        const int g = fi >> 1, ks = fi & 1;
        const int lo = lane & 15, hi = lane >> 4;
        const int row = g * 16 + lo;                   // c, 0..127
        const int d0  = ks * 32 + hi * 8;
        float4 a = *(const float4*)&Wz[row * DI + d0];
        float4 b = *(const float4*)&Wz[row * DI + d0 + 4];
        union { u16 s8[8]; uint4 v; } pk;
        pk.s8[0] = f2h(a.x); pk.s8[1] = f2h(a.y); pk.s8[2] = f2h(a.z); pk.s8[3] = f2h(a.w);
        pk.s8[4] = f2h(b.x); pk.s8[5] = f2h(b.y); pk.s8[6] = f2h(b.z); pk.s8[7] = f2h(b.w);
        *(uint4*)&Wzf[(size_t)t * 8] = pk.v;
    }
}

// ---------------------------------------------------------------------------
// Kernel 1: q/k/v projection as one fp16 MFMA GEMM per 64-token block
// (validated rounds 7/9). W-frags from global (L2); LDS = F-tile + v^T.
// q,k fp16 [n][p][d]; v bf16 TRANSPOSED [n][d][p].
// ---------------------------------------------------------------------------
__global__ __launch_bounds__(256) void proj_kernel(
    const float* __restrict__ F, const u16* __restrict__ Wf,
    const float* __restrict__ bq, const float* __restrict__ bk,
    const float* __restrict__ bv,
    u16* __restrict__ qo, u16* __restrict__ ko, u16* __restrict__ vto)
{
    __shared__ __align__(16) u16 Fl[64 * 128];    // 16384 B fp16 [tok][c], swizzled
    __shared__ __align__(16) u16 Vt[64 * 72];     //  9216 B bf16 v^T restage

    const int tid  = threadIdx.x;
    const int n    = blockIdx.x / NTILE;
    const int p0   = (blockIdx.x % NTILE) * 64;
    const int lane = tid & 63, wave = tid >> 6;
    const int lo   = lane & 15, hi = lane >> 4;

    // --- stage F transposed [tok][c] (fp32 -> fp16), packed u32 writes ---
    const float* Fn = F + (size_t)n * CCH * HW;
    #pragma unroll
    for (int i = 0; i < 4; ++i) {
        int s  = tid + i * 256;                   // 0..1023
        int c0 = (s >> 4) * 2;                    // even channel
        int t0 = (s & 15) * 4;                    // token group
        const float* fp_ = &Fn[(size_t)c0 * HW + p0 + t0];
        float4 fa = *(const float4*)fp_;
        float4 fb = *(const float4*)(fp_ + HW);
        #pragma unroll
        for (int e = 0; e < 4; ++e) {
            int t = t0 + e;
            u32 w = (u32)f2h((&fa.x)[e]) | ((u32)f2h((&fb.x)[e]) << 16);
            *(u32*)&Fl[t * 128 + (((c0 >> 3) ^ (t & 15)) << 3) + (c0 & 7)] = w;
        }
    }
    __syncthreads();

    // --- A-frags: F rows = tokens wave*16 + lo ---
    const int arow = wave * 16 + lo;
    f16x8 af[4];
    #pragma unroll
    for (int ks = 0; ks < 4; ++ks)
        af[ks] = *(const f16x8*)&Fl[arow * 128 + (((ks * 4 + hi) ^ lo) << 3)];

    f32x4 acc[12];
    #pragma unroll
    for (int g = 0; g < 12; ++g)
        #pragma unroll
        for (int r = 0; r < 4; ++r) acc[g][r] = 0.f;

    #pragma unroll
    for (int g = 0; g < 12; ++g) {
        #pragma unroll
        for (int ks = 0; ks < 4; ++ks) {
            f16x8 bf = *(const f16x8*)&Wf[(size_t)((g * 4 + ks) * 64 + lane) * 8];
            acc[g] = __builtin_amdgcn_mfma_f32_16x16x32_f16(af[ks], bf, acc[g], 0, 0, 0);
        }
    }

    // --- epilogue: D[row = token 4hi+r][col = dout g*16+lo] ---
    const int twb = p0 + wave * 16 + 4 * hi;      // + r = global token
    #pragma unroll
    for (int g = 0; g < 4; ++g) {
        float bQ = bq[g * 16 + lo], bK = bk[g * 16 + lo];
        #pragma unroll
        for (int r = 0; r < 4; ++r) {
            size_t off = ((size_t)n * HW + twb + r) * DI + g * 16 + lo;
            qo[off] = f2h(acc[g][r] + bQ);
            ko[off] = f2h(acc[g + 4][r] + bK);
        }
    }
    #pragma unroll
    for (int g = 0; g < 4; ++g) {
        float bV = bv[g * 16 + lo];
        #pragma unroll
        for (int r = 0; r < 4; ++r)
            Vt[(g * 16 + lo) * 72 + wave * 16 + 4 * hi + r] = f2bf_rne(acc[g + 8][r] + bV);
    }
    __syncthreads();
    #pragma unroll
    for (int i = 0; i < 2; ++i) {
        int s = tid + i * 256;                    // 0..511
        int d = s >> 3, c8 = (s & 7) * 8;
        *(uint4*)&vto[((size_t)n * DI + d) * HW + p0 + c8] = *(const uint4*)&Vt[d * 72 + c8];
    }
}

// ---------------------------------------------------------------------------
// Kernel 2: one-pass MFMA flash attention (no-max softmax) — round-6
// structure + fp16 QK^T + native __bf16 P casts (validated round 9).
// Only change this round: y partials stored fp16 (combine consumes via MFMA).
// ---------------------------------------------------------------------------
__global__ __launch_bounds__(256, 4) void attn_pass_kernel(
    const u16* __restrict__ q, const u16* __restrict__ k, const u16* __restrict__ vt,
    u16* __restrict__ ypart)
{
    __shared__ __align__(16) u16 smem[16384];     // 32 KiB: K dbuf (fp16) | V dbuf (bf16)
    u16* const Kb0 = smem;
    u16* const Kb1 = smem + 4096;
    u16* const Vb0 = smem + 8192;
    u16* const Vb1 = smem + 12288;

    const int tid  = threadIdx.x;
    const int lane = tid & 63;
    const int wave = tid >> 6;
    const int lo   = lane & 15, hi = lane >> 4;

    // chunked bijective XCD swizzle: 1152 = 8 * 144
    const int bid  = (int)blockIdx.x;
    const int w    = (bid & 7) * 144 + (bid >> 3);
    const int pass = w / (NBATCH * NTILE);
    const int rem  = w % (NBATCH * NTILE);
    const int n    = rem / NTILE;
    const int p0   = (rem % NTILE) * 64;

    const int nb = (pass == 0) ? (n > 0 ? n - 1 : 0)
                               : (n < NBATCH - 1 ? n + 1 : n);
    const u16* kp = k  + (size_t)nb * HW * DI;
    const u16* vp = vt + (size_t)nb * DI * HW;

    // Q fragments (B-operand of swapped QK): lane holds Q[q=lo][d=hi*8+j]
    f16x8 qf0, qf1;
    {
        const u16* qp = q + ((size_t)n * HW + p0 + wave * 16 + lo) * DI + hi * 8;
        qf0 = *(const f16x8*)qp;
        qf1 = *(const f16x8*)(qp + 32);
    }

    // staging geometry: 512 x 16B chunks per 8KB tile; thread covers 2 rows
    const int sch   = tid & 7;
    const int srow0 = tid >> 3;
    const int srow1 = srow0 + 32;
    const int fk0   = (srow0 & 3) | ((srow0 & 8) >> 1);
    const int fk1   = (srow1 & 3) | ((srow1 & 8) >> 1);
    const int koff0 = srow0 * 64 + ((sch ^ fk0) * 8);
    const int koff1 = srow1 * 64 + ((sch ^ fk1) * 8);
    const int voff0 = srow0 * 64 + ((sch ^ (srow0 & 7)) * 8);
    const int voff1 = srow1 * 64 + ((sch ^ (srow1 & 7)) * 8);

    // permuted K A-frag row base: kr_m = krbase + 4*(m&1) + 32*(m>>1)
    const int krbase = 8 * (lo >> 2) + (lo & 3);
    const int xl = lo & 7;

    f32x4 yacc[4];
    #pragma unroll
    for (int nf = 0; nf < 4; ++nf)
        #pragma unroll
        for (int r = 0; r < 4; ++r) yacc[nf][r] = 0.f;
    float lacc = 0.f;

    // prologue: tile0 -> buf0; tile1 -> regs
    uint4 ka0 = *(const uint4*)(kp + (size_t)srow0 * DI + sch * 8);
    uint4 ka1 = *(const uint4*)(kp + (size_t)srow1 * DI + sch * 8);
    uint4 va0 = *(const uint4*)(vp + (size_t)srow0 * HW + sch * 8);
    uint4 va1 = *(const uint4*)(vp + (size_t)srow1 * HW + sch * 8);
    *(uint4*)&Kb0[koff0] = ka0;  *(uint4*)&Kb0[koff1] = ka1;
    *(uint4*)&Vb0[voff0] = va0;  *(uint4*)&Vb0[voff1] = va1;
    ka0 = *(const uint4*)(kp + (size_t)(64 + srow0) * DI + sch * 8);
    ka1 = *(const uint4*)(kp + (size_t)(64 + srow1) * DI + sch * 8);
    va0 = *(const uint4*)(vp + (size_t)srow0 * HW + 64 + sch * 8);
    va1 = *(const uint4*)(vp + (size_t)srow1 * HW + 64 + sch * 8);
    __syncthreads();

    auto body = [&](int t, const u16* Kc, const u16* Vc, u16* Kn, u16* Vn) {
        // --- swapped QK^T with permuted A rows ---
        // st[m][r] = S[key = 8hi + 4(m&1) + r + 32(m>>1)][q = lo]
        f32x4 st[4];
        __builtin_amdgcn_s_setprio(1);
        #pragma unroll
        for (int m = 0; m < 4; ++m) {
            const int kr = krbase + 4 * (m & 1) + 32 * (m >> 1);
            f16x8 a0 = *(const f16x8*)&Kc[kr * 64 + ((hi ^ xl) * 8)];
            f16x8 a1 = *(const f16x8*)&Kc[kr * 64 + (((4 + hi) ^ xl) * 8)];
            f32x4 z = {0.f, 0.f, 0.f, 0.f};
            z = __builtin_amdgcn_mfma_f32_16x16x32_f16(a0, qf0, z, 0, 0, 0);
            z = __builtin_amdgcn_mfma_f32_16x16x32_f16(a1, qf1, z, 0, 0, 0);
            st[m] = z;
        }
        __builtin_amdgcn_s_setprio(0);

        // --- P = exp(S) -> bf16 via native casts; l from unrounded exps ---
        bf16x8 pa0, pa1;
        #pragma unroll
        for (int m = 0; m < 4; ++m) {
            float e0 = __expf(st[m][0]);
            float e1 = __expf(st[m][1]);
            float e2 = __expf(st[m][2]);
            float e3 = __expf(st[m][3]);
            lacc += (e0 + e1) + (e2 + e3);
            __bf16 b0 = (__bf16)e0, b1 = (__bf16)e1, b2 = (__bf16)e2, b3 = (__bf16)e3;
            if (m == 0)      { pa0[0] = b0; pa0[1] = b1; pa0[2] = b2; pa0[3] = b3; }
            else if (m == 1) { pa0[4] = b0; pa0[5] = b1; pa0[6] = b2; pa0[7] = b3; }
            else if (m == 2) { pa1[0] = b0; pa1[1] = b1; pa1[2] = b2; pa1[3] = b3; }
            else             { pa1[4] = b0; pa1[5] = b1; pa1[6] = b2; pa1[7] = b3; }
        }

        // --- PV: Y[q][d] += P(16x64) x V(64k x 64d)  (B from V^T tile) ---
        __builtin_amdgcn_s_setprio(1);
        #pragma unroll
        for (int nf = 0; nf < 4; ++nf) {
            const int vr = nf * 16 + lo;
            bf16x8 v0 = *(const bf16x8*)&Vc[vr * 64 + ((hi ^ xl) * 8)];
            bf16x8 v1 = *(const bf16x8*)&Vc[vr * 64 + (((4 + hi) ^ xl) * 8)];
            yacc[nf] = __builtin_amdgcn_mfma_f32_16x16x32_bf16(pa0, v0, yacc[nf], 0, 0, 0);
            yacc[nf] = __builtin_amdgcn_mfma_f32_16x16x32_bf16(pa1, v1, yacc[nf], 0, 0, 0);
        }
        __builtin_amdgcn_s_setprio(0);

        // --- stage tile t+1 into the other buffer; prefetch t+2 ---
        if (t + 1 < NTILE) {
            *(uint4*)&Kn[koff0] = ka0; *(uint4*)&Kn[koff1] = ka1;
            *(uint4*)&Vn[voff0] = va0; *(uint4*)&Vn[voff1] = va1;
        }
        if (t + 2 < NTILE) {
            int tb = (t + 2) * 64;
            ka0 = *(const uint4*)(kp + (size_t)(tb + srow0) * DI + sch * 8);
            ka1 = *(const uint4*)(kp + (size_t)(tb + srow1) * DI + sch * 8);
            va0 = *(const uint4*)(vp + (size_t)srow0 * HW + tb + sch * 8);
            va1 = *(const uint4*)(vp + (size_t)srow1 * HW + tb + sch * 8);
        }
        __syncthreads();
    };

    #pragma unroll 1
    for (int tt = 0; tt < NTILE; tt += 2) {
        body(tt,     Kb0, Vb0, Kb1, Vb1);
        body(tt + 1, Kb1, Vb1, Kb0, Vb0);
    }

    // --- finalize: reduce l over hi-groups, per-row inv ---
    float l = lacc;
    l += __shfl_xor(l, 16);
    l += __shfl_xor(l, 32);
    float inv = 1.f / l;
    float invq[4];
    #pragma unroll
    for (int r = 0; r < 4; ++r) invq[r] = __shfl(inv, 20 * hi + r);  // q = 4hi+r

    __syncthreads();                           // done with K/V buffers
    u16* yw = smem;                            // [64][72] fp16 restage
    #pragma unroll
    for (int nf = 0; nf < 4; ++nf)
        #pragma unroll
        for (int r = 0; r < 4; ++r)
            yw[(wave * 16 + hi * 4 + r) * 72 + nf * 16 + lo] =
                f2h(yacc[nf][r] * invq[r]);
    __syncthreads();

    u16* yg = ypart + ((size_t)(pass * NBATCH + n) * HW + p0) * DI;
    #pragma unroll
    for (int s = 0; s < 2; ++s) {
        int idx = tid + s * 256;
        int row = idx >> 3, c8 = (idx & 7) * 8;
        *(uint4*)&yg[row * DI + c8] = *(const uint4*)&yw[row * 72 + c8];
    }
}

// ---------------------------------------------------------------------------
// Kernel 3: combine passes + z-projection + residual, via fp16 MFMA.
// z = y0 @ Wz^T + y1 @ Wz^T  (linearity: both accumulate into the same acc)
//   + 2*bz + F.
// Round-9 profile: old scalar combine was 80% stalled on wave-uniform global
// Wz loads (512/thread). Now: A-frags = y rows from global, B-frags = Wzf
// (L2-resident), 32 MFMA/wave; result restaged through LDS (read-side
// conflict-free: bank = lane + c) and stored coalesced.
// ---------------------------------------------------------------------------
__global__ __launch_bounds__(256) void combine_kernel(
    const u16* __restrict__ ypart, const u16* __restrict__ Wzf,
    const float* __restrict__ bz, const float* __restrict__ F,
    float* __restrict__ out)
{
    __shared__ __align__(16) float zs[64 * 129];  // 33024 B
    const int tid  = threadIdx.x;
    const int n    = blockIdx.x / NTILE;
    const int p0   = (blockIdx.x % NTILE) * 64;
    const int lane = tid & 63, wave = tid >> 6;
    const int lo   = lane & 15, hi = lane >> 4;

    // A-frags: token row = p0 + wave*16 + lo, both passes
    const u16* y0 = ypart + ((size_t)n * HW + p0 + wave * 16 + lo) * DI;
    const u16* y1 = ypart + ((size_t)(NBATCH + n) * HW + p0 + wave * 16 + lo) * DI;
    f16x8 a00 = *(const f16x8*)(y0 + hi * 8);
    f16x8 a01 = *(const f16x8*)(y0 + 32 + hi * 8);
    f16x8 a10 = *(const f16x8*)(y1 + hi * 8);
    f16x8 a11 = *(const f16x8*)(y1 + 32 + hi * 8);

    f32x4 acc[8];
    #pragma unroll
    for (int g = 0; g < 8; ++g)
        #pragma unroll
        for (int r = 0; r < 4; ++r) acc[g][r] = 0.f;

    #pragma unroll
    for (int g = 0; g < 8; ++g) {
        f16x8 b0 = *(const f16x8*)&Wzf[(size_t)((g * 2 + 0) * 64 + lane) * 8];
        f16x8 b1 = *(const f16x8*)&Wzf[(size_t)((g * 2 + 1) * 64 + lane) * 8];
        acc[g] = __builtin_amdgcn_mfma_f32_16x16x32_f16(a00, b0, acc[g], 0, 0, 0);
        acc[g] = __builtin_amdgcn_mfma_f32_16x16x32_f16(a01, b1, acc[g], 0, 0, 0);
        acc[g] = __builtin_amdgcn_mfma_f32_16x16x32_f16(a10, b0, acc[g], 0, 0, 0);
        acc[g] = __builtin_amdgcn_mfma_f32_16x16x32_f16(a11, b1, acc[g], 0, 0, 0);
    }

    // D[row = token wave*16+4hi+r][col = c g*16+lo] -> LDS restage
    #pragma unroll
    for (int g = 0; g < 8; ++g)
        #pragma unroll
        for (int r = 0; r < 4; ++r)
            zs[(wave * 16 + 4 * hi + r) * 129 + g * 16 + lo] = acc[g][r];
    __syncthreads();

    // coalesced store: token = lane, 32 channels per thread
    #pragma unroll 4
    for (int i = 0; i < 32; ++i) {
        int c = wave + 4 * i;
        size_t gi = (size_t)(n * CCH + c) * HW + p0 + lane;
        out[gi] = zs[lane * 129 + c] + 2.f * bz[c] + F[gi];
    }
}

extern "C" void kernel_launch(void* const* d_in, const int* in_sizes, int n_in,
                              void* d_out, int out_size, void* d_ws, size_t ws_size,
                              hipStream_t stream) {
    const float* F  = (const float*)d_in[0];
    const float* Wq = (const float*)d_in[1];
    const float* bq = (const float*)d_in[2];
    const float* Wk = (const float*)d_in[3];
    const float* bk = (const float*)d_in[4];
    const float* Wv = (const float*)d_in[5];
    const float* bv = (const float*)d_in[6];
    const float* Wz = (const float*)d_in[7];
    const float* bz = (const float*)d_in[8];
    float* outp = (float*)d_out;

    const size_t tok = (size_t)NBATCH * HW * DI;   // 2,359,296 elements
    u16* qb  = (u16*)d_ws;                         // fp16
    u16* kb  = qb  + tok;                          // fp16
    u16* vtb = kb  + tok;                          // bf16, transposed
    u16* yp  = vtb + tok;                          // 2*tok fp16 partials
    u16* wf  = yp  + 2 * tok;                      // 24576 fp16 frag-ordered Wq/Wk/Wv
    u16* wzf = wf  + 24576;                        //  8192 fp16 frag-ordered Wz
    // total ws: (5*tok + 32768) * 2B ~= 23.7 MB

    wprep_kernel<<<16, 256, 0, stream>>>(Wq, Wk, Wv, Wz, wf, wzf);
    proj_kernel<<<NBATCH * NTILE, 256, 0, stream>>>(F, wf, bq, bk, bv, qb, kb, vtb);
    attn_pass_kernel<<<2 * NBATCH * NTILE, 256, 0, stream>>>(qb, kb, vtb, yp);
    combine_kernel<<<NBATCH * NTILE, 256, 0, stream>>>(yp, wzf, bz, F, outp);
}